// Round 1
// baseline (619.282 us; speedup 1.0000x reference)
//
#include <hip/hip_runtime.h>

#define NH 16
#define DM 1024
#define SQ 2048
#define BT 4
#define SCALE 0.125f  // 1/sqrt(64)

typedef __attribute__((ext_vector_type(8))) short bf16x8;
typedef __attribute__((ext_vector_type(4))) short sh4;
typedef __attribute__((ext_vector_type(4))) float f4;
typedef __attribute__((ext_vector_type(4))) float fv4;
typedef unsigned short u16;

__device__ __forceinline__ u16 f2bf(float f) {
    union { float f; unsigned u; } v; v.f = f;
    unsigned r = v.u + 0x7FFFu + ((v.u >> 16) & 1u);
    return (u16)(r >> 16);
}

#define GLD16(gp, lp) __builtin_amdgcn_global_load_lds( \
    (const __attribute__((address_space(1))) void*)(gp), \
    (__attribute__((address_space(3))) void*)(lp), 16, 0, 0)

// ---------------- fp32 -> bf16 elementwise (vectorized) ----------------
__global__ __launch_bounds__(256) void cvt_x(const float* __restrict__ x, u16* __restrict__ y) {
    int i = blockIdx.x * 256 + threadIdx.x;
    fv4 v = ((const fv4*)x)[i];
    sh4 r;
    r[0] = (short)f2bf(v[0]); r[1] = (short)f2bf(v[1]);
    r[2] = (short)f2bf(v[2]); r[3] = (short)f2bf(v[3]);
    ((sh4*)y)[i] = r;
}

// ---------------- fp32 W[K][N] -> bf16 Wt[N][K] (LDS transpose) ----------------
__global__ __launch_bounds__(256) void cvt_wT(const float* __restrict__ Wsrc, u16* __restrict__ Wt) {
    __shared__ float t[64][65];
    int r0 = blockIdx.x * 64, c0 = blockIdx.y * 64;
    #pragma unroll
    for (int i = 0; i < 16; ++i) {
        int idx = i * 256 + threadIdx.x;
        int r = idx >> 6, c = idx & 63;
        t[r][c] = Wsrc[(size_t)(r0 + r) * DM + c0 + c];
    }
    __syncthreads();
    #pragma unroll
    for (int i = 0; i < 16; ++i) {
        int idx = i * 256 + threadIdx.x;
        int n = idx >> 6, k = idx & 63;
        Wt[(size_t)(c0 + n) * DM + r0 + k] = f2bf(t[k][n]);
    }
}

// ---------------- projection GEMM: [8192,1024] x [1024,1024] + bias ----------------
// A bf16 [M,K] row-major; Bt bf16 [N,K] row-major; out bf16:
//   vmode 0: [B,H,S,64]   vmode 1: [B,H,64,S] (transposed for PV B-operand)
__global__ __launch_bounds__(256) void gemm_proj(const u16* __restrict__ A, const u16* __restrict__ Bt,
                                                 const float* __restrict__ bias, u16* __restrict__ outp,
                                                 int vmode) {
    __shared__ u16 As[128 * 64];
    __shared__ u16 Bs[128 * 64];
    int tid = threadIdx.x;
    int w = tid >> 6, lane = tid & 63, quad = lane >> 4, l16 = lane & 15;
    int wm = w >> 1, wn = w & 1;
    int r8 = lane >> 3, cg = (lane & 7) ^ r8;  // XOR-swizzled global chunk for this lane's LDS slot
    const u16* Ag = A + (size_t)blockIdx.x * 128 * DM;
    const u16* Bg = Bt + (size_t)blockIdx.y * 128 * DM;

    f4 acc[4][4];
    #pragma unroll
    for (int mt = 0; mt < 4; ++mt)
        #pragma unroll
        for (int nt = 0; nt < 4; ++nt) acc[mt][nt] = f4{0.f, 0.f, 0.f, 0.f};

    for (int kt = 0; kt < 16; ++kt) {
        int kofs = kt * 64 + cg * 8;
        #pragma unroll
        for (int c = 0; c < 4; ++c) {
            int rbase = w * 32 + c * 8;
            GLD16(Ag + (size_t)(rbase + r8) * DM + kofs, &As[rbase * 64]);
            GLD16(Bg + (size_t)(rbase + r8) * DM + kofs, &Bs[rbase * 64]);
        }
        __syncthreads();
        #pragma unroll
        for (int ks = 0; ks < 2; ++ks) {
            bf16x8 afr[4], bfr[4];
            #pragma unroll
            for (int mt = 0; mt < 4; ++mt) {
                int row = wm * 64 + mt * 16 + l16;
                int ch = (ks * 4 + quad) ^ (row & 7);
                afr[mt] = *(const bf16x8*)&As[row * 64 + ch * 8];
            }
            #pragma unroll
            for (int nt = 0; nt < 4; ++nt) {
                int row = wn * 64 + nt * 16 + l16;
                int ch = (ks * 4 + quad) ^ (row & 7);
                bfr[nt] = *(const bf16x8*)&Bs[row * 64 + ch * 8];
            }
            #pragma unroll
            for (int mt = 0; mt < 4; ++mt)
                #pragma unroll
                for (int nt = 0; nt < 4; ++nt)
                    acc[mt][nt] = __builtin_amdgcn_mfma_f32_16x16x32_bf16(afr[mt], bfr[nt], acc[mt][nt], 0, 0, 0);
        }
        __syncthreads();
    }

    #pragma unroll
    for (int nt = 0; nt < 4; ++nt) {
        int ncol = blockIdx.y * 128 + wn * 64 + nt * 16 + l16;
        float bn = bias[ncol];
        int h = ncol >> 6, d = ncol & 63;
        #pragma unroll
        for (int mt = 0; mt < 4; ++mt) {
            int mbase = blockIdx.x * 128 + wm * 64 + mt * 16 + quad * 4;
            int bidx = mbase >> 11, s0 = mbase & 2047;
            if (vmode == 0) {
                size_t base = ((size_t)bidx * NH + h) * SQ;
                #pragma unroll
                for (int reg = 0; reg < 4; ++reg)
                    outp[(base + s0 + reg) * 64 + d] = f2bf(acc[mt][nt][reg] + bn);
            } else {
                sh4 pk;
                #pragma unroll
                for (int reg = 0; reg < 4; ++reg) pk[reg] = (short)f2bf(acc[mt][nt][reg] + bn);
                *(sh4*)&outp[(((size_t)bidx * NH + h) * 64 + d) * SQ + s0] = pk;
            }
        }
    }
}

// ---------------- flash attention: 1 wave = 32 q-rows, KT=64, online softmax ----------------
__device__ __forceinline__ float redmax16(float v) {
    v = fmaxf(v, __shfl_xor(v, 1)); v = fmaxf(v, __shfl_xor(v, 2));
    v = fmaxf(v, __shfl_xor(v, 4)); v = fmaxf(v, __shfl_xor(v, 8));
    return v;
}
__device__ __forceinline__ float redsum16(float v) {
    v += __shfl_xor(v, 1); v += __shfl_xor(v, 2);
    v += __shfl_xor(v, 4); v += __shfl_xor(v, 8);
    return v;
}

__global__ __launch_bounds__(256) void attn(const u16* __restrict__ qw, const u16* __restrict__ kw,
                                            const u16* __restrict__ vtw, const int* __restrict__ mask,
                                            float* __restrict__ outp) {
    __shared__ short P[4][32 * 72];  // per-wave P tile [32 rows][64 + 8 pad cols], row stride 144B (16B-aligned)
    int tid = threadIdx.x;
    int w = tid >> 6, lane = tid & 63, quad = lane >> 4, l16 = lane & 15;
    int bh = blockIdx.y, b = bh >> 4, h = bh & 15;
    int qbase = blockIdx.x * 128 + w * 32;
    const u16* qp = qw + (size_t)bh * SQ * 64;
    const u16* kp = kw + (size_t)bh * SQ * 64;
    const u16* vp = vtw + (size_t)bh * 64 * SQ;
    const int* mp = mask + b * SQ;
    short* Pw = (short*)P[w];

    bf16x8 aq[2][2];
    #pragma unroll
    for (int mt = 0; mt < 2; ++mt)
        #pragma unroll
        for (int ks = 0; ks < 2; ++ks)
            aq[mt][ks] = *(const bf16x8*)&qp[(size_t)(qbase + mt * 16 + l16) * 64 + ks * 32 + quad * 8];

    f4 o[2][4];
    float mrow[2][4], lrow[2][4], alpha[2][4], rsum[2][4];
    #pragma unroll
    for (int mt = 0; mt < 2; ++mt) {
        #pragma unroll
        for (int nt = 0; nt < 4; ++nt) o[mt][nt] = f4{0.f, 0.f, 0.f, 0.f};
        #pragma unroll
        for (int reg = 0; reg < 4; ++reg) { mrow[mt][reg] = -1e30f; lrow[mt][reg] = 0.f; }
    }

    for (int kb = 0; kb < 32; ++kb) {
        int k0 = kb * 64;
        // QK^T: B-operand frags straight from global (L2-resident K)
        bf16x8 bk[4][2];
        #pragma unroll
        for (int nt = 0; nt < 4; ++nt)
            #pragma unroll
            for (int ks = 0; ks < 2; ++ks)
                bk[nt][ks] = *(const bf16x8*)&kp[(size_t)(k0 + nt * 16 + l16) * 64 + ks * 32 + quad * 8];
        f4 S[2][4];
        #pragma unroll
        for (int mt = 0; mt < 2; ++mt)
            #pragma unroll
            for (int nt = 0; nt < 4; ++nt) {
                f4 s = f4{0.f, 0.f, 0.f, 0.f};
                s = __builtin_amdgcn_mfma_f32_16x16x32_bf16(aq[mt][0], bk[nt][0], s, 0, 0, 0);
                s = __builtin_amdgcn_mfma_f32_16x16x32_bf16(aq[mt][1], bk[nt][1], s, 0, 0, 0);
                S[mt][nt] = s;
            }
        // scale + key-padding mask (per C-layout column = this lane's key)
        float bias[4];
        #pragma unroll
        for (int nt = 0; nt < 4; ++nt)
            bias[nt] = mp[k0 + nt * 16 + l16] ? 0.f : -__builtin_inff();
        #pragma unroll
        for (int mt = 0; mt < 2; ++mt)
            #pragma unroll
            for (int nt = 0; nt < 4; ++nt)
                S[mt][nt] = S[mt][nt] * SCALE + bias[nt];
        // online softmax: rows live across the 16-lane group (row = quad*4+reg)
        #pragma unroll
        for (int mt = 0; mt < 2; ++mt)
            #pragma unroll
            for (int reg = 0; reg < 4; ++reg) {
                float r = fmaxf(fmaxf(S[mt][0][reg], S[mt][1][reg]), fmaxf(S[mt][2][reg], S[mt][3][reg]));
                r = redmax16(r);
                float mn = fmaxf(mrow[mt][reg], r);
                alpha[mt][reg] = __expf(mrow[mt][reg] - mn);
                mrow[mt][reg] = mn;
                rsum[mt][reg] = 0.f;
            }
        #pragma unroll
        for (int mt = 0; mt < 2; ++mt)
            #pragma unroll
            for (int nt = 0; nt < 4; ++nt) {
                #pragma unroll
                for (int reg = 0; reg < 4; ++reg) {
                    float p = __expf(S[mt][nt][reg] - mrow[mt][reg]);
                    rsum[mt][reg] += p;
                    Pw[(mt * 16 + quad * 4 + reg) * 72 + nt * 16 + l16] = (short)f2bf(p);
                }
            }
        #pragma unroll
        for (int mt = 0; mt < 2; ++mt)
            #pragma unroll
            for (int reg = 0; reg < 4; ++reg)
                lrow[mt][reg] = lrow[mt][reg] * alpha[mt][reg] + redsum16(rsum[mt][reg]);
        #pragma unroll
        for (int mt = 0; mt < 2; ++mt)
            #pragma unroll
            for (int nt = 0; nt < 4; ++nt)
                #pragma unroll
                for (int reg = 0; reg < 4; ++reg)
                    o[mt][nt][reg] *= alpha[mt][reg];
        // PV: P via LDS round-trip (C-layout -> A-operand layout), V^T frags from global
        #pragma unroll
        for (int kk = 0; kk < 2; ++kk) {
            bf16x8 ap[2], bv[4];
            #pragma unroll
            for (int mt = 0; mt < 2; ++mt)
                ap[mt] = *(const bf16x8*)&Pw[(mt * 16 + l16) * 72 + kk * 32 + quad * 8];
            #pragma unroll
            for (int nt = 0; nt < 4; ++nt)
                bv[nt] = *(const bf16x8*)&vp[(size_t)(nt * 16 + l16) * SQ + k0 + kk * 32 + quad * 8];
            #pragma unroll
            for (int mt = 0; mt < 2; ++mt)
                #pragma unroll
                for (int nt = 0; nt < 4; ++nt)
                    o[mt][nt] = __builtin_amdgcn_mfma_f32_16x16x32_bf16(ap[mt], bv[nt], o[mt][nt], 0, 0, 0);
        }
    }

    #pragma unroll
    for (int mt = 0; mt < 2; ++mt)
        #pragma unroll
        for (int reg = 0; reg < 4; ++reg) {
            float inv = 1.f / lrow[mt][reg];
            int row = qbase + mt * 16 + quad * 4 + reg;
            size_t obase = ((size_t)b * SQ + row) * DM + h * 64;
            #pragma unroll
            for (int nt = 0; nt < 4; ++nt)
                outp[obase + nt * 16 + l16] = o[mt][nt][reg] * inv;
        }
}

extern "C" void kernel_launch(void* const* d_in, const int* in_sizes, int n_in,
                              void* d_out, int out_size, void* d_ws, size_t ws_size,
                              hipStream_t stream) {
    (void)in_sizes; (void)n_in; (void)out_size; (void)ws_size;
    const float* Q  = (const float*)d_in[0];
    const float* K  = (const float*)d_in[1];
    const float* V  = (const float*)d_in[2];
    const int* mask = (const int*)d_in[3];
    const float* Wq = (const float*)d_in[4];
    const float* bq = (const float*)d_in[5];
    const float* Wk = (const float*)d_in[6];
    const float* bk = (const float*)d_in[7];
    const float* Wv = (const float*)d_in[8];
    const float* bv = (const float*)d_in[9];
    float* out = (float*)d_out;
    char* ws = (char*)d_ws;
    // ws layout (66 MB total): q 16MB | k 16MB | v^T 16MB | xbuf 16MB | wbuf 2MB
    u16* q_ws = (u16*)(ws);
    u16* k_ws = (u16*)(ws + (size_t)16 * 1024 * 1024);
    u16* v_ws = (u16*)(ws + (size_t)32 * 1024 * 1024);
    u16* xbuf = (u16*)(ws + (size_t)48 * 1024 * 1024);
    u16* wbuf = (u16*)(ws + (size_t)64 * 1024 * 1024);

    dim3 gGemm(64, 8), gW(16, 16);
    // Q path
    cvt_x<<<8192, 256, 0, stream>>>(Q, xbuf);
    cvt_wT<<<gW, 256, 0, stream>>>(Wq, wbuf);
    gemm_proj<<<gGemm, 256, 0, stream>>>(xbuf, wbuf, bq, q_ws, 0);
    // K path
    cvt_x<<<8192, 256, 0, stream>>>(K, xbuf);
    cvt_wT<<<gW, 256, 0, stream>>>(Wk, wbuf);
    gemm_proj<<<gGemm, 256, 0, stream>>>(xbuf, wbuf, bk, k_ws, 0);
    // V path (transposed output)
    cvt_x<<<8192, 256, 0, stream>>>(V, xbuf);
    cvt_wT<<<gW, 256, 0, stream>>>(Wv, wbuf);
    gemm_proj<<<gGemm, 256, 0, stream>>>(xbuf, wbuf, bv, v_ws, 1);
    // attention
    attn<<<dim3(16, 64), 256, 0, stream>>>(q_ws, k_ws, v_ws, mask, out);
}

// Round 2
// 362.042 us; speedup vs baseline: 1.7105x; 1.7105x over previous
//
#include <hip/hip_runtime.h>

#define NH 16
#define DM 1024
#define SQ 2048
#define BT 4

typedef __attribute__((ext_vector_type(8))) short bf16x8;
typedef __attribute__((ext_vector_type(4))) short sh4;
typedef __attribute__((ext_vector_type(4))) float f4;
typedef __attribute__((ext_vector_type(4))) float fv4;
typedef unsigned short u16;

#define M2BIAS 23.083120654f   /* 16 * log2(e) */
#define SCALE2 0.18033688f     /* (1/8) * log2(e) */

__device__ __forceinline__ u16 f2bf(float f) {
    union { float f; unsigned u; } v; v.f = f;
    unsigned r = v.u + 0x7FFFu + ((v.u >> 16) & 1u);
    return (u16)(r >> 16);
}

__device__ __forceinline__ float fast_exp2(float x) {
#if __has_builtin(__builtin_amdgcn_exp2f)
    return __builtin_amdgcn_exp2f(x);
#else
    return exp2f(x);
#endif
}

#define GLD16(gp, lp) __builtin_amdgcn_global_load_lds( \
    (const __attribute__((address_space(1))) void*)(gp), \
    (__attribute__((address_space(3))) void*)(lp), 16, 0, 0)

// ---------------- fp32 -> bf16 elementwise (vectorized) ----------------
__global__ __launch_bounds__(256) void cvt_x(const float* __restrict__ x, u16* __restrict__ y) {
    int i = blockIdx.x * 256 + threadIdx.x;
    fv4 v = ((const fv4*)x)[i];
    sh4 r;
    r[0] = (short)f2bf(v[0]); r[1] = (short)f2bf(v[1]);
    r[2] = (short)f2bf(v[2]); r[3] = (short)f2bf(v[3]);
    ((sh4*)y)[i] = r;
}

// ---------------- fp32 W[K][N] -> bf16 Wt[N][K] (LDS transpose) ----------------
__global__ __launch_bounds__(256) void cvt_wT(const float* __restrict__ Wsrc, u16* __restrict__ Wt) {
    __shared__ float t[64][65];
    int r0 = blockIdx.x * 64, c0 = blockIdx.y * 64;
    #pragma unroll
    for (int i = 0; i < 16; ++i) {
        int idx = i * 256 + threadIdx.x;
        int r = idx >> 6, c = idx & 63;
        t[r][c] = Wsrc[(size_t)(r0 + r) * DM + c0 + c];
    }
    __syncthreads();
    #pragma unroll
    for (int i = 0; i < 16; ++i) {
        int idx = i * 256 + threadIdx.x;
        int n = idx >> 6, k = idx & 63;
        Wt[(size_t)(c0 + n) * DM + r0 + k] = f2bf(t[k][n]);
    }
}

// ---------------- mask -> float bias (-M2 for keep, -inf for masked) ----------------
__global__ __launch_bounds__(256) void mk_mbias(const int* __restrict__ mask, float* __restrict__ mb) {
    int i = blockIdx.x * 256 + threadIdx.x;
    mb[i] = mask[i] ? -M2BIAS : -__builtin_inff();
}

// ---------------- projection GEMM: [8192,1024] x [1024,1024] + bias ----------------
__global__ __launch_bounds__(256) void gemm_proj(const u16* __restrict__ A, const u16* __restrict__ Bt,
                                                 const float* __restrict__ bias, u16* __restrict__ outp,
                                                 int vmode) {
    __shared__ u16 As[128 * 64];
    __shared__ u16 Bs[128 * 64];
    int tid = threadIdx.x;
    int w = tid >> 6, lane = tid & 63, quad = lane >> 4, l16 = lane & 15;
    int wm = w >> 1, wn = w & 1;
    int r8 = lane >> 3, cg = (lane & 7) ^ r8;
    const u16* Ag = A + (size_t)blockIdx.x * 128 * DM;
    const u16* Bg = Bt + (size_t)blockIdx.y * 128 * DM;

    f4 acc[4][4];
    #pragma unroll
    for (int mt = 0; mt < 4; ++mt)
        #pragma unroll
        for (int nt = 0; nt < 4; ++nt) acc[mt][nt] = f4{0.f, 0.f, 0.f, 0.f};

    for (int kt = 0; kt < 16; ++kt) {
        int kofs = kt * 64 + cg * 8;
        #pragma unroll
        for (int c = 0; c < 4; ++c) {
            int rbase = w * 32 + c * 8;
            GLD16(Ag + (size_t)(rbase + r8) * DM + kofs, &As[rbase * 64]);
            GLD16(Bg + (size_t)(rbase + r8) * DM + kofs, &Bs[rbase * 64]);
        }
        __syncthreads();
        #pragma unroll
        for (int ks = 0; ks < 2; ++ks) {
            bf16x8 afr[4], bfr[4];
            #pragma unroll
            for (int mt = 0; mt < 4; ++mt) {
                int row = wm * 64 + mt * 16 + l16;
                int ch = (ks * 4 + quad) ^ (row & 7);
                afr[mt] = *(const bf16x8*)&As[row * 64 + ch * 8];
            }
            #pragma unroll
            for (int nt = 0; nt < 4; ++nt) {
                int row = wn * 64 + nt * 16 + l16;
                int ch = (ks * 4 + quad) ^ (row & 7);
                bfr[nt] = *(const bf16x8*)&Bs[row * 64 + ch * 8];
            }
            #pragma unroll
            for (int mt = 0; mt < 4; ++mt)
                #pragma unroll
                for (int nt = 0; nt < 4; ++nt)
                    acc[mt][nt] = __builtin_amdgcn_mfma_f32_16x16x32_bf16(afr[mt], bfr[nt], acc[mt][nt], 0, 0, 0);
        }
        __syncthreads();
    }

    #pragma unroll
    for (int nt = 0; nt < 4; ++nt) {
        int ncol = blockIdx.y * 128 + wn * 64 + nt * 16 + l16;
        float bn = bias[ncol];
        int h = ncol >> 6, d = ncol & 63;
        #pragma unroll
        for (int mt = 0; mt < 4; ++mt) {
            int mbase = blockIdx.x * 128 + wm * 64 + mt * 16 + quad * 4;
            int bidx = mbase >> 11, s0 = mbase & 2047;
            if (vmode == 0) {
                size_t base = ((size_t)bidx * NH + h) * SQ;
                #pragma unroll
                for (int reg = 0; reg < 4; ++reg)
                    outp[(base + s0 + reg) * 64 + d] = f2bf(acc[mt][nt][reg] + bn);
            } else {
                sh4 pk;
                #pragma unroll
                for (int reg = 0; reg < 4; ++reg) pk[reg] = (short)f2bf(acc[mt][nt][reg] + bn);
                *(sh4*)&outp[(((size_t)bidx * NH + h) * 64 + d) * SQ + s0] = pk;
            }
        }
    }
}

// ---------------- flash attention ----------------
// Block: 4 waves x 32 q-rows = 128 q-rows. K/V tiles (64 keys) staged in LDS,
// double-buffered via global_load_lds with XOR chunk swizzle; fixed-max softmax
// (p = 2^(s*log2e/8 + mbias), mbias = -16*log2e or -inf) => no per-iter shuffles.
__device__ __forceinline__ float redsum16(float v) {
    v += __shfl_xor(v, 1); v += __shfl_xor(v, 2);
    v += __shfl_xor(v, 4); v += __shfl_xor(v, 8);
    return v;
}

__global__ __launch_bounds__(256, 3) void attn(const u16* __restrict__ qw, const u16* __restrict__ kw,
                                               const u16* __restrict__ vtw, const float* __restrict__ mbias,
                                               float* __restrict__ outp) {
    __shared__ u16 Ks[2][64 * 64];   // [key row][64 k-elems], chunk-swizzled
    __shared__ u16 Vs[2][64 * 64];   // [d row][64 keys], chunk-swizzled
    __shared__ short P[4][32 * 72];  // per-wave P tile, row stride 144B
    int tid = threadIdx.x;
    int w = tid >> 6, lane = tid & 63, quad = lane >> 4, l16 = lane & 15;
    int r8 = lane >> 3, sl = lane & 7;
    int bh = blockIdx.y, b = bh >> 4, h = bh & 15;
    int qbase = blockIdx.x * 128 + w * 32;
    const u16* qp = qw + (size_t)bh * SQ * 64;
    const u16* kp = kw + (size_t)bh * SQ * 64;
    const u16* vp = vtw + (size_t)bh * 64 * SQ;
    const float* mbp = mbias + b * SQ;
    short* Pw = (short*)P[w];

    bf16x8 aq[2][2];
    #pragma unroll
    for (int mt = 0; mt < 2; ++mt)
        #pragma unroll
        for (int ks = 0; ks < 2; ++ks)
            aq[mt][ks] = *(const bf16x8*)&qp[(size_t)(qbase + mt * 16 + l16) * 64 + ks * 32 + quad * 8];

    f4 o[2][4];
    float lrow[2][4];
    #pragma unroll
    for (int mt = 0; mt < 2; ++mt) {
        #pragma unroll
        for (int nt = 0; nt < 4; ++nt) o[mt][nt] = f4{0.f, 0.f, 0.f, 0.f};
        #pragma unroll
        for (int reg = 0; reg < 4; ++reg) lrow[mt][reg] = 0.f;
    }

    // stage 64-key K and V^T tiles into LDS buffer `buf` (wave w loads rows w*16..w*16+15)
    auto stage = [&](int buf, int k0) {
        #pragma unroll
        for (int j = 0; j < 2; ++j) {
            int row = w * 16 + j * 8 + r8;
            int gsl = sl ^ (row & 7);
            GLD16(kp + (size_t)(k0 + row) * 64 + gsl * 8, &Ks[buf][(w * 16 + j * 8) * 64]);
            GLD16(vp + (size_t)row * SQ + k0 + gsl * 8, &Vs[buf][(w * 16 + j * 8) * 64]);
        }
    };

    stage(0, 0);
    for (int kb = 0; kb < 32; ++kb) {
        int buf = kb & 1;
        int k0 = kb * 64;
        __syncthreads();  // staging of `buf` complete; prev reads of buf^1 done
        if (kb + 1 < 32) stage(buf ^ 1, k0 + 64);

        // QK^T from LDS
        bf16x8 bk[4][2];
        #pragma unroll
        for (int nt = 0; nt < 4; ++nt)
            #pragma unroll
            for (int ks = 0; ks < 2; ++ks) {
                int r = nt * 16 + l16;
                int slot = (ks * 4 + quad) ^ (r & 7);
                bk[nt][ks] = *(const bf16x8*)&Ks[buf][r * 64 + slot * 8];
            }
        f4 S[2][4];
        #pragma unroll
        for (int mt = 0; mt < 2; ++mt)
            #pragma unroll
            for (int nt = 0; nt < 4; ++nt) {
                f4 s = f4{0.f, 0.f, 0.f, 0.f};
                s = __builtin_amdgcn_mfma_f32_16x16x32_bf16(aq[mt][0], bk[nt][0], s, 0, 0, 0);
                s = __builtin_amdgcn_mfma_f32_16x16x32_bf16(aq[mt][1], bk[nt][1], s, 0, 0, 0);
                S[mt][nt] = s;
            }
        float bias2[4];
        #pragma unroll
        for (int nt = 0; nt < 4; ++nt)
            bias2[nt] = mbp[k0 + nt * 16 + l16];
        // p = 2^(s*SCALE2 + bias2); accumulate row sums per-lane; P -> LDS (trunc bf16)
        #pragma unroll
        for (int mt = 0; mt < 2; ++mt)
            #pragma unroll
            for (int nt = 0; nt < 4; ++nt) {
                #pragma unroll
                for (int reg = 0; reg < 4; ++reg) {
                    float p = fast_exp2(S[mt][nt][reg] * SCALE2 + bias2[nt]);
                    lrow[mt][reg] += p;
                    Pw[(mt * 16 + quad * 4 + reg) * 72 + nt * 16 + l16] =
                        (short)(__float_as_uint(p) >> 16);
                }
            }
        // PV from LDS (P round-trip per-wave; V^T staged)
        #pragma unroll
        for (int kk = 0; kk < 2; ++kk) {
            bf16x8 ap[2], bv[4];
            #pragma unroll
            for (int mt = 0; mt < 2; ++mt)
                ap[mt] = *(const bf16x8*)&Pw[(mt * 16 + l16) * 72 + kk * 32 + quad * 8];
            #pragma unroll
            for (int nt = 0; nt < 4; ++nt) {
                int d = nt * 16 + l16;
                int slot = (kk * 4 + quad) ^ (d & 7);
                bv[nt] = *(const bf16x8*)&Vs[buf][d * 64 + slot * 8];
            }
            #pragma unroll
            for (int mt = 0; mt < 2; ++mt)
                #pragma unroll
                for (int nt = 0; nt < 4; ++nt)
                    o[mt][nt] = __builtin_amdgcn_mfma_f32_16x16x32_bf16(ap[mt], bv[nt], o[mt][nt], 0, 0, 0);
        }
    }

    #pragma unroll
    for (int mt = 0; mt < 2; ++mt)
        #pragma unroll
        for (int reg = 0; reg < 4; ++reg) {
            float inv = 1.f / redsum16(lrow[mt][reg]);
            int row = qbase + mt * 16 + quad * 4 + reg;
            size_t obase = ((size_t)b * SQ + row) * DM + h * 64;
            #pragma unroll
            for (int nt = 0; nt < 4; ++nt)
                outp[obase + nt * 16 + l16] = o[mt][nt][reg] * inv;
        }
}

extern "C" void kernel_launch(void* const* d_in, const int* in_sizes, int n_in,
                              void* d_out, int out_size, void* d_ws, size_t ws_size,
                              hipStream_t stream) {
    (void)in_sizes; (void)n_in; (void)out_size; (void)ws_size;
    const float* Q  = (const float*)d_in[0];
    const float* K  = (const float*)d_in[1];
    const float* V  = (const float*)d_in[2];
    const int* mask = (const int*)d_in[3];
    const float* Wq = (const float*)d_in[4];
    const float* bq = (const float*)d_in[5];
    const float* Wk = (const float*)d_in[6];
    const float* bk = (const float*)d_in[7];
    const float* Wv = (const float*)d_in[8];
    const float* bv = (const float*)d_in[9];
    float* out = (float*)d_out;
    char* ws = (char*)d_ws;
    // ws layout (66 MB): q 16MB | k 16MB | v^T 16MB | xbuf 16MB | wbuf 2MB
    u16* q_ws = (u16*)(ws);
    u16* k_ws = (u16*)(ws + (size_t)16 * 1024 * 1024);
    u16* v_ws = (u16*)(ws + (size_t)32 * 1024 * 1024);
    u16* xbuf = (u16*)(ws + (size_t)48 * 1024 * 1024);
    u16* wbuf = (u16*)(ws + (size_t)64 * 1024 * 1024);
    float* mb = (float*)(ws + (size_t)48 * 1024 * 1024);  // reuses xbuf after gemm3

    dim3 gGemm(64, 8), gW(16, 16);
    cvt_x<<<8192, 256, 0, stream>>>(Q, xbuf);
    cvt_wT<<<gW, 256, 0, stream>>>(Wq, wbuf);
    gemm_proj<<<gGemm, 256, 0, stream>>>(xbuf, wbuf, bq, q_ws, 0);
    cvt_x<<<8192, 256, 0, stream>>>(K, xbuf);
    cvt_wT<<<gW, 256, 0, stream>>>(Wk, wbuf);
    gemm_proj<<<gGemm, 256, 0, stream>>>(xbuf, wbuf, bk, k_ws, 0);
    cvt_x<<<8192, 256, 0, stream>>>(V, xbuf);
    cvt_wT<<<gW, 256, 0, stream>>>(Wv, wbuf);
    gemm_proj<<<gGemm, 256, 0, stream>>>(xbuf, wbuf, bv, v_ws, 1);
    mk_mbias<<<32, 256, 0, stream>>>(mask, mb);  // xbuf region free after gemm3
    attn<<<dim3(16, 64), 256, 0, stream>>>(q_ws, k_ws, v_ws, mb, out);
}